// Round 1
// baseline (128.753 us; speedup 1.0000x reference)
//
#include <hip/hip_runtime.h>

// EmbedDNF: B=128, IN_F=256, HID=512, OUT=128, E=8 (fp32, e innermost)
//
// impl = 1 - w*(1-xnor) = A + x*Bv ; A = 1 - w*s ; Bv = 2*w*s - w
// H[b,h,e]   = prod_i (A[i,h,e] + x[b,i,e]*Bv[i,h,e])
// out[b,o,e] = 1 - prod_h (1 - dw[h,o,e]*H[b,h,e])
//
// Laws (R4-R11): (1) acc <= 32 VGPR, inner loop = streaming VMEM +
// immediate-offset LDS broadcasts, NO restructuring of stage1 (4 spill
// regressions); (2) broadcast operands in LDS; (3) no device-scope fences
// (R9); (4) keep >= 4 blocks/CU resident (R11).
// This round (R12): stage2 thread-tile rebalance 8b x 1o -> 2b x 16o
// (acc still 32 VGPR). Effect: per-thread LDS hv reads 8/ii -> 2/ii
// (stage2 LDS delivery 256 MB -> 64 MB), H-tile 8 KB -> 2 KB, P1 read
// exactly once (64 MB -> 16 MB). Cost: dw stream x4 (L2-resident, cheap).
// stage1 / comb2 unchanged.
//
// ws: P1 [8][512][128][8] fp32 @ 0        (16 MB)  stage1 i-split partials
//     P2 [16][128][128][8] fp32 @ 4194304 (8 MB)   stage2 h-split partials

#define LD4(p) (*(const float4*)(p))

static __device__ __forceinline__ float4 f4mul(float4 a, float4 b) {
    return make_float4(a.x*b.x, a.y*b.y, a.z*b.z, a.w*b.w);
}
static __device__ __forceinline__ float4 f4fma(float4 a, float4 b, float4 c) {
    return make_float4(fmaf(a.x,b.x,c.x), fmaf(a.y,b.y,c.y),
                       fmaf(a.z,b.z,c.z), fmaf(a.w,b.w,c.w));
}
static __device__ __forceinline__ float4 f4nfma1(float4 d, float4 h) {  // 1-d*h
    return make_float4(fmaf(-d.x,h.x,1.0f), fmaf(-d.y,h.y,1.0f),
                       fmaf(-d.z,h.z,1.0f), fmaf(-d.w,h.w,1.0f));
}

// ---------------------------------------------------------------------------
// Stage 1. Grid 2048 = hg16 (32 h, low bits: XCD L2 slicing) x bg16 (8 b) x
// ks8 (32 i). Block 256 = 4 waves = 4 i-subchunks of 8. Lane = eh2 x hl32;
// thread tile 8b x 1h x 4e (acc = 32 VGPR, R7-proven). UNCHANGED.
// ---------------------------------------------------------------------------
__global__ __launch_bounds__(256, 4) void k_stage1(
    const float* __restrict__ in,   // [128][256][8]
    const float* __restrict__ cw,   // [256][512][8]
    const float* __restrict__ cs,   // [256][512][8]
    float* __restrict__ P1)         // ws: [8][512][128][8]
{
    __shared__ float lds[4096];              // 16 KB: x-tile [0,2048) then combine
    const int t    = threadIdx.x;
    const int lane = t & 63;
    const int kc   = t >> 6;                 // 0..3
    const int eh   = lane & 1;
    const int hl   = lane >> 1;              // 0..31
    const int hg   = blockIdx.x & 15;
    const int bg   = (blockIdx.x >> 4) & 15;
    const int ks   = blockIdx.x >> 8;        // 0..7
    const int b0   = bg * 8;
    const int h    = hg * 32 + hl;
    const int e0   = eh * 4;

    // stage x[b0:+8][ks*32:+32][0:8] -> lds (layout [b][il][e]), coalesced
    {
        float4* xs4 = (float4*)lds;
        #pragma unroll
        for (int k = 0; k < 2; ++k) {
            const int f4  = t + k * 256;     // 0..511
            const int b   = f4 >> 6;
            const int col = f4 & 63;         // float4 within 256-float row
            xs4[f4] = LD4(in + (b0 + b) * 2048 + ks * 256 + col * 4);
        }
    }
    __syncthreads();

    const int i0 = ks * 32 + kc * 8;
    const float* pw = cw + i0 * 4096 + h * 8 + e0;
    const float* ps = cs + i0 * 4096 + h * 8 + e0;
    const float* xbase = lds + kc * 64 + e0;    // + b*256 + ii*8 (immediates)

    float4 acc[8];
    #pragma unroll
    for (int b = 0; b < 8; ++b) acc[b] = make_float4(1.f, 1.f, 1.f, 1.f);

    #pragma unroll
    for (int ii = 0; ii < 8; ++ii) {
        const float4 wv = LD4(pw);
        const float4 sv = LD4(ps);
        pw += 4096; ps += 4096;
        const float4 p  = f4mul(wv, sv);
        const float4 A  = make_float4(1.f - p.x, 1.f - p.y, 1.f - p.z, 1.f - p.w);
        const float4 Bv = make_float4(fmaf(2.f, p.x, -wv.x), fmaf(2.f, p.y, -wv.y),
                                      fmaf(2.f, p.z, -wv.z), fmaf(2.f, p.w, -wv.w));
        #pragma unroll
        for (int b = 0; b < 8; ++b) {
            const float4 xv = LD4(xbase + b * 256 + ii * 8);
            acc[b] = f4mul(acc[b], f4fma(xv, Bv, A));
        }
    }

    __syncthreads();                         // x-tile dead; reuse lds
    #pragma unroll
    for (int phase = 0; phase < 2; ++phase) {
        if (phase) __syncthreads();          // protect phase-0 reads
        #pragma unroll
        for (int j = 0; j < 4; ++j)
            *(float4*)&lds[kc * 1024 + j * 256 + hl * 8 + e0] = acc[phase * 4 + j];
        __syncthreads();
        {   // combine 4 kc; thread t -> one float4 of the 1024-float tile
            const int o4 = t * 4;            // j*256 + hl2*8 + eq*4
            float4 m = LD4(&lds[o4]);
            #pragma unroll
            for (int c = 1; c < 4; ++c) m = f4mul(m, LD4(&lds[c * 1024 + o4]));
            const int j   = o4 >> 8;
            const int hl2 = (o4 >> 3) & 31;
            const int eq  = o4 & 7;          // 0 or 4
            *(float4*)(P1 + ks * 524288 + (hg * 32 + hl2) * 1024
                          + (b0 + phase * 4 + j) * 8 + eq) = m;
        }
    }
}

// ---------------------------------------------------------------------------
// Stage 2 (R12 rebalance). Grid 1024 = bg64 (2 b, low bits) x ks16 (32 h).
// Block 256 = 4 waves = 4 h-subchunks of 8. Lane = eh2 x ol32;
// thread tile 2b x 16o x 4e as acc[q4][b2] (32 VGPR, law 1).
// Prologue: H-tile [32 h][2 b][8 e] (2 KB) = product of 8 P1 copies -> LDS;
// each P1 element read exactly once across the grid (16 MB total).
// Step: 4 streaming VMEM (dw, 4 KB contiguous per wave) + 2 immediate-offset
// ds_read_b128 broadcasts (hv reused across 4 o-quadrants) + 64 VALU. 8 steps.
// kc-partials combined in 2 phases (phase = b); ks-partials -> P2.
// 16 KB LDS, ~70 VGPR -> 4 blocks/CU (law 4), consecutive blocks share the
// same 128 KB dw slice (ks in high bits) -> dw stays L2-resident per XCD.
// ---------------------------------------------------------------------------
__global__ __launch_bounds__(256, 4) void k_stage2(
    const float* __restrict__ dw,   // [512][128][8]
    const float* __restrict__ P1,   // ws: [8][512][128][8]
    float* __restrict__ P2)         // ws: [16][128][128][8]
{
    __shared__ float lds[4096];              // 16 KB: H-tile [0,512) then combine
    const int t    = threadIdx.x;
    const int lane = t & 63;
    const int kc   = t >> 6;                 // 0..3
    const int eh   = lane & 1;
    const int ol   = lane >> 1;              // 0..31
    const int bg   = blockIdx.x & 63;        // low bits: b-slicing
    const int ks   = blockIdx.x >> 6;        // 0..15
    const int b0   = bg * 2;
    const int e0   = eh * 4;
    const int h0   = ks * 32;

    // H-tile: product of the 8 i-split partials, layout [hl][b][e] = 512 floats
    if (t < 128) {
        const int hl = t >> 2;
        const int b  = (t >> 1) & 1;
        const int eq = (t & 1) * 4;
        const float* q = P1 + (h0 + hl) * 1024 + (b0 + b) * 8 + eq;
        float4 m = LD4(q);
        #pragma unroll
        for (int c = 1; c < 8; ++c) m = f4mul(m, LD4(q + c * 524288));
        ((float4*)lds)[t] = m;
    }
    __syncthreads();

    const float* pd = dw + (h0 + kc * 8) * 1024 + ol * 8 + e0;
    const float* hbase = lds + kc * 128 + e0;   // + ii*16 + b*8 (immediates)

    float4 acc[4][2];                        // [o-quadrant][b] = 32 VGPR
    #pragma unroll
    for (int q = 0; q < 4; ++q)
        #pragma unroll
        for (int b = 0; b < 2; ++b) acc[q][b] = make_float4(1.f, 1.f, 1.f, 1.f);

    #pragma unroll
    for (int ii = 0; ii < 8; ++ii) {
        const float4 dv0 = LD4(pd);
        const float4 dv1 = LD4(pd + 256);
        const float4 dv2 = LD4(pd + 512);
        const float4 dv3 = LD4(pd + 768);
        pd += 1024;
        const float4 hv0 = LD4(hbase + ii * 16);      // b=0
        const float4 hv1 = LD4(hbase + ii * 16 + 8);  // b=1
        acc[0][0] = f4mul(acc[0][0], f4nfma1(dv0, hv0));
        acc[1][0] = f4mul(acc[1][0], f4nfma1(dv1, hv0));
        acc[2][0] = f4mul(acc[2][0], f4nfma1(dv2, hv0));
        acc[3][0] = f4mul(acc[3][0], f4nfma1(dv3, hv0));
        acc[0][1] = f4mul(acc[0][1], f4nfma1(dv0, hv1));
        acc[1][1] = f4mul(acc[1][1], f4nfma1(dv1, hv1));
        acc[2][1] = f4mul(acc[2][1], f4nfma1(dv2, hv1));
        acc[3][1] = f4mul(acc[3][1], f4nfma1(dv3, hv1));
    }

    __syncthreads();                         // H-tile dead; reuse lds
    // 2 phases (phase = b): partial[kc][q4][ol32][e8] = 1024 floats per kc
    #pragma unroll
    for (int phase = 0; phase < 2; ++phase) {
        if (phase) __syncthreads();          // protect phase-0 reads
        #pragma unroll
        for (int q = 0; q < 4; ++q)
            *(float4*)&lds[kc * 1024 + q * 256 + ol * 8 + e0] = acc[q][phase];
        __syncthreads();
        {   // combine 4 kc; thread t -> one float4 of the 1024-float tile
            const int o4 = t * 4;            // q*256 + ol2*8 + eq*4
            float4 m = LD4(&lds[o4]);
            #pragma unroll
            for (int c = 1; c < 4; ++c) m = f4mul(m, LD4(&lds[c * 1024 + o4]));
            const int q   = o4 >> 8;
            const int ol2 = (o4 >> 3) & 31;
            const int eq  = o4 & 7;          // 0 or 4
            *(float4*)(P2 + ks * 131072 + (b0 + phase) * 1024
                          + (q * 32 + ol2) * 8 + eq) = m;
        }
    }
}

// ---------------------------------------------------------------------------
// Final: out = 1 - prod over the 16 h-split partials. 8 MB read, 0.5 MB write.
// 16 independent loads per thread -> deep MLP. UNCHANGED.
// ---------------------------------------------------------------------------
__global__ __launch_bounds__(256, 4) void k_comb2(
    const float* __restrict__ P2,   // ws: [16][128][128][8]
    float* __restrict__ out)        // [128][128][8]
{
    const int idx4 = blockIdx.x * 256 + threadIdx.x;   // 0..32767
    float4 m = LD4(P2 + idx4 * 4);
    #pragma unroll
    for (int c = 1; c < 16; ++c)
        m = f4mul(m, LD4(P2 + c * 131072 + idx4 * 4));
    const float4 r = make_float4(1.f - m.x, 1.f - m.y, 1.f - m.z, 1.f - m.w);
    *(float4*)(out + idx4 * 4) = r;
}

extern "C" void kernel_launch(void* const* d_in, const int* in_sizes, int n_in,
                              void* d_out, int out_size, void* d_ws, size_t ws_size,
                              hipStream_t stream)
{
    const float* in = (const float*)d_in[0];   // [128][256][8]
    const float* cw = (const float*)d_in[1];   // [256][512][8]
    const float* cs = (const float*)d_in[2];   // [256][512][8]
    const float* dw = (const float*)d_in[3];   // [512][128][8]
    float* outp = (float*)d_out;               // [128][128][8]
    float* P1   = (float*)d_ws;                // 16 MB
    float* P2   = (float*)d_ws + 4194304;      // 8 MB

    k_stage1<<<2048, 256, 0, stream>>>(in, cw, cs, P1);
    k_stage2<<<1024, 256, 0, stream>>>(dw, P1, P2);
    k_comb2<<<128, 256, 0, stream>>>(P2, outp);
}

// Round 2
// 94.006 us; speedup vs baseline: 1.3696x; 1.3696x over previous
//
#include <hip/hip_runtime.h>

// EmbedDNF: B=128, IN_F=256, HID=512, OUT=128, E=8 (fp32, e innermost)
//
// impl = 1 - w*(1-xnor) = A + x*Bv ; A = 1 - w*s ; Bv = 2*w*s - w
// H[b,h,e]   = prod_i (A[i,h,e] + x[b,i,e]*Bv[i,h,e])
// out[b,o,e] = 1 - prod_h (1 - dw[h,o,e]*H[b,h,e])
//
// Laws (R4-R13): (1) acc <= 32 VGPR, inner loop = streaming VMEM +
// immediate-offset LDS broadcasts, NO restructuring (4 spill regressions;
// stage1 sits exactly at the 64-VGPR / 8-blocks-per-CU boundary — do not
// add register pressure); (2) broadcast operands in LDS; (3) no
// device-scope fences (R9); (4) keep >= 4 blocks/CU resident (R11);
// (5) R12 LESSON: stage2 is latency-bound, not LDS-bound — the 2b x 16o
// rebalance (serial 128-thread prologue + scattered 64B P1 gathers)
// regressed 16 -> 48 us. Reverted.
// This round (R13): stage2 = R11 structure, blockIdx remap ONLY: ks in low
// 4 bits -> XCD = ks&7 pins each XCD to 2 P1 h-slices (2 MB) + dw slice
// (256 KB) < 4 MB L2, so the og4 re-reads of P1 hit L2 instead of L3.
//
// ws: P1 [8][512][128][8] fp32 @ 0        (16 MB)  stage1 i-split partials
//     P2 [16][128][128][8] fp32 @ 4194304 (8 MB)   stage2 h-split partials

#define LD4(p) (*(const float4*)(p))

static __device__ __forceinline__ float4 f4mul(float4 a, float4 b) {
    return make_float4(a.x*b.x, a.y*b.y, a.z*b.z, a.w*b.w);
}
static __device__ __forceinline__ float4 f4fma(float4 a, float4 b, float4 c) {
    return make_float4(fmaf(a.x,b.x,c.x), fmaf(a.y,b.y,c.y),
                       fmaf(a.z,b.z,c.z), fmaf(a.w,b.w,c.w));
}
static __device__ __forceinline__ float4 f4nfma1(float4 d, float4 h) {  // 1-d*h
    return make_float4(fmaf(-d.x,h.x,1.0f), fmaf(-d.y,h.y,1.0f),
                       fmaf(-d.z,h.z,1.0f), fmaf(-d.w,h.w,1.0f));
}

// ---------------------------------------------------------------------------
// Stage 1. Grid 2048 = hg16 (32 h, low bits: XCD L2 slicing) x bg16 (8 b) x
// ks8 (32 i). Block 256 = 4 waves = 4 i-subchunks of 8. Lane = eh2 x hl32;
// thread tile 8b x 1h x 4e (acc = 32 VGPR, R7-proven). UNCHANGED.
// ---------------------------------------------------------------------------
__global__ __launch_bounds__(256, 4) void k_stage1(
    const float* __restrict__ in,   // [128][256][8]
    const float* __restrict__ cw,   // [256][512][8]
    const float* __restrict__ cs,   // [256][512][8]
    float* __restrict__ P1)         // ws: [8][512][128][8]
{
    __shared__ float lds[4096];              // 16 KB: x-tile [0,2048) then combine
    const int t    = threadIdx.x;
    const int lane = t & 63;
    const int kc   = t >> 6;                 // 0..3
    const int eh   = lane & 1;
    const int hl   = lane >> 1;              // 0..31
    const int hg   = blockIdx.x & 15;
    const int bg   = (blockIdx.x >> 4) & 15;
    const int ks   = blockIdx.x >> 8;        // 0..7
    const int b0   = bg * 8;
    const int h    = hg * 32 + hl;
    const int e0   = eh * 4;

    // stage x[b0:+8][ks*32:+32][0:8] -> lds (layout [b][il][e]), coalesced
    {
        float4* xs4 = (float4*)lds;
        #pragma unroll
        for (int k = 0; k < 2; ++k) {
            const int f4  = t + k * 256;     // 0..511
            const int b   = f4 >> 6;
            const int col = f4 & 63;         // float4 within 256-float row
            xs4[f4] = LD4(in + (b0 + b) * 2048 + ks * 256 + col * 4);
        }
    }
    __syncthreads();

    const int i0 = ks * 32 + kc * 8;
    const float* pw = cw + i0 * 4096 + h * 8 + e0;
    const float* ps = cs + i0 * 4096 + h * 8 + e0;
    const float* xbase = lds + kc * 64 + e0;    // + b*256 + ii*8 (immediates)

    float4 acc[8];
    #pragma unroll
    for (int b = 0; b < 8; ++b) acc[b] = make_float4(1.f, 1.f, 1.f, 1.f);

    #pragma unroll
    for (int ii = 0; ii < 8; ++ii) {
        const float4 wv = LD4(pw);
        const float4 sv = LD4(ps);
        pw += 4096; ps += 4096;
        const float4 p  = f4mul(wv, sv);
        const float4 A  = make_float4(1.f - p.x, 1.f - p.y, 1.f - p.z, 1.f - p.w);
        const float4 Bv = make_float4(fmaf(2.f, p.x, -wv.x), fmaf(2.f, p.y, -wv.y),
                                      fmaf(2.f, p.z, -wv.z), fmaf(2.f, p.w, -wv.w));
        #pragma unroll
        for (int b = 0; b < 8; ++b) {
            const float4 xv = LD4(xbase + b * 256 + ii * 8);
            acc[b] = f4mul(acc[b], f4fma(xv, Bv, A));
        }
    }

    __syncthreads();                         // x-tile dead; reuse lds
    #pragma unroll
    for (int phase = 0; phase < 2; ++phase) {
        if (phase) __syncthreads();          // protect phase-0 reads
        #pragma unroll
        for (int j = 0; j < 4; ++j)
            *(float4*)&lds[kc * 1024 + j * 256 + hl * 8 + e0] = acc[phase * 4 + j];
        __syncthreads();
        {   // combine 4 kc; thread t -> one float4 of the 1024-float tile
            const int o4 = t * 4;            // j*256 + hl2*8 + eq*4
            float4 m = LD4(&lds[o4]);
            #pragma unroll
            for (int c = 1; c < 4; ++c) m = f4mul(m, LD4(&lds[c * 1024 + o4]));
            const int j   = o4 >> 8;
            const int hl2 = (o4 >> 3) & 31;
            const int eq  = o4 & 7;          // 0 or 4
            *(float4*)(P1 + ks * 524288 + (hg * 32 + hl2) * 1024
                          + (b0 + phase * 4 + j) * 8 + eq) = m;
        }
    }
}

// ---------------------------------------------------------------------------
// Stage 2 (R11 structure, R13 blockIdx remap). Grid 1024 = ks16 (32 h, LOW
// bits: XCD = ks&7 pins P1 h-slices + dw slice to one XCD's L2) x og4
// (32 o) x bg16 (8 b). Block 256 = 4 waves = 4 h-subchunks of 8.
// Lane = eh2 x ol32; thread tile 8b x 1o x 4e (acc = 32 VGPR, R7-proven).
// Prologue: H-tile [32 h][8 b][8 e] (8 KB) = product of 8 P1 copies -> LDS,
// 256 threads x 16 parallel loads. Step: 1 streaming VMEM (dw contiguous
// 1 KB wave-load) + 8 immediate-offset ds_read_b128 broadcasts + 64 VALU.
// Per-XCD working set: 2 x 1 MB P1 ks-slices + 2 x 128 KB dw < 4 MB L2, so
// the og4 re-reads of P1 (4x16 MB VMEM) are L2 hits; P1 leaves L3 once.
// ---------------------------------------------------------------------------
__global__ __launch_bounds__(256, 4) void k_stage2(
    const float* __restrict__ dw,   // [512][128][8]
    const float* __restrict__ P1,   // ws: [8][512][128][8]
    float* __restrict__ P2)         // ws: [16][128][128][8]
{
    __shared__ float lds[4096];              // 16 KB: H-tile [0,2048) then combine
    const int t    = threadIdx.x;
    const int lane = t & 63;
    const int kc   = t >> 6;                 // 0..3
    const int eh   = lane & 1;
    const int ol   = lane >> 1;              // 0..31
    const int ks   = blockIdx.x & 15;        // LOW bits: XCD = ks&7
    const int og   = (blockIdx.x >> 4) & 3;
    const int bg   = blockIdx.x >> 6;        // 0..15
    const int b0   = bg * 8;
    const int o    = og * 32 + ol;
    const int e0   = eh * 4;
    const int h0   = ks * 32;

    // H-tile: product of the 8 i-split partials, layout [hl][b][e]
    {
        float4* ht4 = (float4*)lds;
        #pragma unroll
        for (int k = 0; k < 2; ++k) {
            const int f4  = t + k * 256;     // 0..511
            const int hl  = f4 >> 4;
            const int rem = f4 & 15;         // b*2 + eq
            const float* q = P1 + (h0 + hl) * 1024 + b0 * 8 + rem * 4;
            float4 m = LD4(q);
            #pragma unroll
            for (int c = 1; c < 8; ++c) m = f4mul(m, LD4(q + c * 524288));
            ht4[f4] = m;
        }
    }
    __syncthreads();

    const float* pd = dw + (h0 + kc * 8) * 1024 + o * 8 + e0;
    const float* hbase = lds + kc * 512 + e0;   // + ii*64 + b*8 (immediates)

    float4 acc[8];
    #pragma unroll
    for (int b = 0; b < 8; ++b) acc[b] = make_float4(1.f, 1.f, 1.f, 1.f);

    #pragma unroll
    for (int ii = 0; ii < 8; ++ii) {
        const float4 dv = LD4(pd);
        pd += 1024;
        #pragma unroll
        for (int b = 0; b < 8; ++b) {
            const float4 hv = LD4(hbase + ii * 64 + b * 8);
            acc[b] = f4mul(acc[b], f4nfma1(dv, hv));
        }
    }

    __syncthreads();                         // H-tile dead; reuse lds
    // 2 phases of 4 b: partial[kc][j4][ol32][e8] = 1024 floats per kc
    #pragma unroll
    for (int phase = 0; phase < 2; ++phase) {
        if (phase) __syncthreads();
        #pragma unroll
        for (int j = 0; j < 4; ++j)
            *(float4*)&lds[kc * 1024 + j * 256 + ol * 8 + e0] = acc[phase * 4 + j];
        __syncthreads();
        {
            const int o4 = t * 4;            // j*256 + ol2*8 + eq*4
            float4 m = LD4(&lds[o4]);
            #pragma unroll
            for (int c = 1; c < 4; ++c) m = f4mul(m, LD4(&lds[c * 1024 + o4]));
            const int j   = o4 >> 8;
            const int ol2 = (o4 >> 3) & 31;
            const int eq  = o4 & 7;
            *(float4*)(P2 + ks * 131072 + (b0 + phase * 4 + j) * 1024
                          + (og * 32 + ol2) * 8 + eq) = m;
        }
    }
}

// ---------------------------------------------------------------------------
// Final: out = 1 - prod over the 16 h-split partials. 8 MB read, 0.5 MB write.
// 16 independent loads per thread -> deep MLP. UNCHANGED.
// ---------------------------------------------------------------------------
__global__ __launch_bounds__(256, 4) void k_comb2(
    const float* __restrict__ P2,   // ws: [16][128][128][8]
    float* __restrict__ out)        // [128][128][8]
{
    const int idx4 = blockIdx.x * 256 + threadIdx.x;   // 0..32767
    float4 m = LD4(P2 + idx4 * 4);
    #pragma unroll
    for (int c = 1; c < 16; ++c)
        m = f4mul(m, LD4(P2 + c * 131072 + idx4 * 4));
    const float4 r = make_float4(1.f - m.x, 1.f - m.y, 1.f - m.z, 1.f - m.w);
    *(float4*)(out + idx4 * 4) = r;
}

extern "C" void kernel_launch(void* const* d_in, const int* in_sizes, int n_in,
                              void* d_out, int out_size, void* d_ws, size_t ws_size,
                              hipStream_t stream)
{
    const float* in = (const float*)d_in[0];   // [128][256][8]
    const float* cw = (const float*)d_in[1];   // [256][512][8]
    const float* cs = (const float*)d_in[2];   // [256][512][8]
    const float* dw = (const float*)d_in[3];   // [512][128][8]
    float* outp = (float*)d_out;               // [128][128][8]
    float* P1   = (float*)d_ws;                // 16 MB
    float* P2   = (float*)d_ws + 4194304;      // 8 MB

    k_stage1<<<2048, 256, 0, stream>>>(in, cw, cs, P1);
    k_stage2<<<1024, 256, 0, stream>>>(dw, P1, P2);
    k_comb2<<<128, 256, 0, stream>>>(P2, outp);
}

// Round 3
// 89.203 us; speedup vs baseline: 1.4434x; 1.0538x over previous
//
#include <hip/hip_runtime.h>

// EmbedDNF: B=128, IN_F=256, HID=512, OUT=128, E=8 (fp32, e innermost)
//
// impl = 1 - w*(1-xnor) = A + x*Bv ; A = 1 - w*s ; Bv = 2*w*s - w
// H[b,h,e]   = prod_i (A[i,h,e] + x[b,i,e]*Bv[i,h,e])
// out[b,o,e] = 1 - prod_h (1 - dw[h,o,e]*H[b,h,e])
//
// Laws (R4-R14): (1) acc <= 32 VGPR, inner loop = streaming VMEM +
// immediate-offset LDS broadcasts, NO restructuring (4 spill regressions;
// stage1 sits at the 64-VGPR / 8-blocks-per-CU boundary); (2) broadcast
// operands in LDS; (3) no device-scope fences (R9); (4) keep >= 4
// blocks/CU resident (R11); (5) R12 LESSON: these kernels are
// latency-bound (VALUBusy ~4%) — optimize the LATENCY CLASS of the
// repeated VMEM stream, not LDS/VALU counts.
// Ledger (confirmed R0-R13): dur = fill ~43 (untouchable harness poison,
// in-window) + s1 ~35 + s2 ~13 + comb2 ~3.
// This round (R14): stage1 blockIdx remap ONLY. Old: XCD = hg&7 -> per-XCD
// repeated cw/cs set = 4 MB (= L2) + 6 MB streaming pollution -> thrash,
// re-reads at L3/HBM latency. New: XCD = (hg&3, ks&1) -> hot set 1 MB
// (128i x 128h x 2 arrays), all 16 bg-siblings still same-XCD -> cw/cs
// fetched once, re-read 16x from L2 at ~200 cyc.
//
// ws: P1 [8][512][128][8] fp32 @ 0        (16 MB)  stage1 i-split partials
//     P2 [16][128][128][8] fp32 @ 4194304 (8 MB)   stage2 h-split partials

#define LD4(p) (*(const float4*)(p))

static __device__ __forceinline__ float4 f4mul(float4 a, float4 b) {
    return make_float4(a.x*b.x, a.y*b.y, a.z*b.z, a.w*b.w);
}
static __device__ __forceinline__ float4 f4fma(float4 a, float4 b, float4 c) {
    return make_float4(fmaf(a.x,b.x,c.x), fmaf(a.y,b.y,c.y),
                       fmaf(a.z,b.z,c.z), fmaf(a.w,b.w,c.w));
}
static __device__ __forceinline__ float4 f4nfma1(float4 d, float4 h) {  // 1-d*h
    return make_float4(fmaf(-d.x,h.x,1.0f), fmaf(-d.y,h.y,1.0f),
                       fmaf(-d.z,h.z,1.0f), fmaf(-d.w,h.w,1.0f));
}

// ---------------------------------------------------------------------------
// Stage 1. Grid 2048. R14 decode: bits [1:0]=hg-lo, [2]=ks-lo, [4:3]=hg-hi,
// [6:5]=ks-hi, [10:7]=bg. XCD = bid&7 = (hg&3)|(ks&1)<<2: per XCD hg in
// {a,a+4,a+8,a+12} (128 h), ks in {b,b+2,b+4,b+6} (128 i), all bg -> hot
// cw/cs set 1 MB, 16x L2 reuse. Block 256 = 4 waves = 4 i-subchunks of 8.
// Lane = eh2 x hl32; thread tile 8b x 1h x 4e (acc = 32 VGPR, R7-proven).
// Inner loop / LDS / epilogue byte-identical to R13.
// ---------------------------------------------------------------------------
__global__ __launch_bounds__(256, 4) void k_stage1(
    const float* __restrict__ in,   // [128][256][8]
    const float* __restrict__ cw,   // [256][512][8]
    const float* __restrict__ cs,   // [256][512][8]
    float* __restrict__ P1)         // ws: [8][512][128][8]
{
    __shared__ float lds[4096];              // 16 KB: x-tile [0,2048) then combine
    const int t    = threadIdx.x;
    const int lane = t & 63;
    const int kc   = t >> 6;                 // 0..3
    const int eh   = lane & 1;
    const int hl   = lane >> 1;              // 0..31
    const int bid  = blockIdx.x;
    const int hg   = (bid & 3) | (((bid >> 3) & 3) << 2);    // 0..15
    const int ks   = ((bid >> 2) & 1) | (((bid >> 5) & 3) << 1); // 0..7
    const int bg   = bid >> 7;                               // 0..15
    const int b0   = bg * 8;
    const int h    = hg * 32 + hl;
    const int e0   = eh * 4;

    // stage x[b0:+8][ks*32:+32][0:8] -> lds (layout [b][il][e]), coalesced
    {
        float4* xs4 = (float4*)lds;
        #pragma unroll
        for (int k = 0; k < 2; ++k) {
            const int f4  = t + k * 256;     // 0..511
            const int b   = f4 >> 6;
            const int col = f4 & 63;         // float4 within 256-float row
            xs4[f4] = LD4(in + (b0 + b) * 2048 + ks * 256 + col * 4);
        }
    }
    __syncthreads();

    const int i0 = ks * 32 + kc * 8;
    const float* pw = cw + i0 * 4096 + h * 8 + e0;
    const float* ps = cs + i0 * 4096 + h * 8 + e0;
    const float* xbase = lds + kc * 64 + e0;    // + b*256 + ii*8 (immediates)

    float4 acc[8];
    #pragma unroll
    for (int b = 0; b < 8; ++b) acc[b] = make_float4(1.f, 1.f, 1.f, 1.f);

    #pragma unroll
    for (int ii = 0; ii < 8; ++ii) {
        const float4 wv = LD4(pw);
        const float4 sv = LD4(ps);
        pw += 4096; ps += 4096;
        const float4 p  = f4mul(wv, sv);
        const float4 A  = make_float4(1.f - p.x, 1.f - p.y, 1.f - p.z, 1.f - p.w);
        const float4 Bv = make_float4(fmaf(2.f, p.x, -wv.x), fmaf(2.f, p.y, -wv.y),
                                      fmaf(2.f, p.z, -wv.z), fmaf(2.f, p.w, -wv.w));
        #pragma unroll
        for (int b = 0; b < 8; ++b) {
            const float4 xv = LD4(xbase + b * 256 + ii * 8);
            acc[b] = f4mul(acc[b], f4fma(xv, Bv, A));
        }
    }

    __syncthreads();                         // x-tile dead; reuse lds
    #pragma unroll
    for (int phase = 0; phase < 2; ++phase) {
        if (phase) __syncthreads();          // protect phase-0 reads
        #pragma unroll
        for (int j = 0; j < 4; ++j)
            *(float4*)&lds[kc * 1024 + j * 256 + hl * 8 + e0] = acc[phase * 4 + j];
        __syncthreads();
        {   // combine 4 kc; thread t -> one float4 of the 1024-float tile
            const int o4 = t * 4;            // j*256 + hl2*8 + eq*4
            float4 m = LD4(&lds[o4]);
            #pragma unroll
            for (int c = 1; c < 4; ++c) m = f4mul(m, LD4(&lds[c * 1024 + o4]));
            const int j   = o4 >> 8;
            const int hl2 = (o4 >> 3) & 31;
            const int eq  = o4 & 7;          // 0 or 4
            *(float4*)(P1 + ks * 524288 + (hg * 32 + hl2) * 1024
                          + (b0 + phase * 4 + j) * 8 + eq) = m;
        }
    }
}

// ---------------------------------------------------------------------------
// Stage 2 (R11 structure, R13 remap — UNCHANGED). Grid 1024 = ks16 (low
// bits: XCD = ks&7 pins P1 h-slices + dw slice in L2) x og4 x bg16.
// Block 256 = 4 waves; lane = eh2 x ol32; thread tile 8b x 1o x 4e.
// ---------------------------------------------------------------------------
__global__ __launch_bounds__(256, 4) void k_stage2(
    const float* __restrict__ dw,   // [512][128][8]
    const float* __restrict__ P1,   // ws: [8][512][128][8]
    float* __restrict__ P2)         // ws: [16][128][128][8]
{
    __shared__ float lds[4096];              // 16 KB: H-tile [0,2048) then combine
    const int t    = threadIdx.x;
    const int lane = t & 63;
    const int kc   = t >> 6;                 // 0..3
    const int eh   = lane & 1;
    const int ol   = lane >> 1;              // 0..31
    const int ks   = blockIdx.x & 15;        // LOW bits: XCD = ks&7
    const int og   = (blockIdx.x >> 4) & 3;
    const int bg   = blockIdx.x >> 6;        // 0..15
    const int b0   = bg * 8;
    const int o    = og * 32 + ol;
    const int e0   = eh * 4;
    const int h0   = ks * 32;

    // H-tile: product of the 8 i-split partials, layout [hl][b][e]
    {
        float4* ht4 = (float4*)lds;
        #pragma unroll
        for (int k = 0; k < 2; ++k) {
            const int f4  = t + k * 256;     // 0..511
            const int hl  = f4 >> 4;
            const int rem = f4 & 15;         // b*2 + eq
            const float* q = P1 + (h0 + hl) * 1024 + b0 * 8 + rem * 4;
            float4 m = LD4(q);
            #pragma unroll
            for (int c = 1; c < 8; ++c) m = f4mul(m, LD4(q + c * 524288));
            ht4[f4] = m;
        }
    }
    __syncthreads();

    const float* pd = dw + (h0 + kc * 8) * 1024 + o * 8 + e0;
    const float* hbase = lds + kc * 512 + e0;   // + ii*64 + b*8 (immediates)

    float4 acc[8];
    #pragma unroll
    for (int b = 0; b < 8; ++b) acc[b] = make_float4(1.f, 1.f, 1.f, 1.f);

    #pragma unroll
    for (int ii = 0; ii < 8; ++ii) {
        const float4 dv = LD4(pd);
        pd += 1024;
        #pragma unroll
        for (int b = 0; b < 8; ++b) {
            const float4 hv = LD4(hbase + ii * 64 + b * 8);
            acc[b] = f4mul(acc[b], f4nfma1(dv, hv));
        }
    }

    __syncthreads();                         // H-tile dead; reuse lds
    // 2 phases of 4 b: partial[kc][j4][ol32][e8] = 1024 floats per kc
    #pragma unroll
    for (int phase = 0; phase < 2; ++phase) {
        if (phase) __syncthreads();
        #pragma unroll
        for (int j = 0; j < 4; ++j)
            *(float4*)&lds[kc * 1024 + j * 256 + ol * 8 + e0] = acc[phase * 4 + j];
        __syncthreads();
        {
            const int o4 = t * 4;            // j*256 + ol2*8 + eq*4
            float4 m = LD4(&lds[o4]);
            #pragma unroll
            for (int c = 1; c < 4; ++c) m = f4mul(m, LD4(&lds[c * 1024 + o4]));
            const int j   = o4 >> 8;
            const int ol2 = (o4 >> 3) & 31;
            const int eq  = o4 & 7;
            *(float4*)(P2 + ks * 131072 + (b0 + phase * 4 + j) * 1024
                          + (og * 32 + ol2) * 8 + eq) = m;
        }
    }
}

// ---------------------------------------------------------------------------
// Final: out = 1 - prod over the 16 h-split partials. 8 MB read, 0.5 MB write.
// 16 independent loads per thread -> deep MLP. UNCHANGED.
// ---------------------------------------------------------------------------
__global__ __launch_bounds__(256, 4) void k_comb2(
    const float* __restrict__ P2,   // ws: [16][128][128][8]
    float* __restrict__ out)        // [128][128][8]
{
    const int idx4 = blockIdx.x * 256 + threadIdx.x;   // 0..32767
    float4 m = LD4(P2 + idx4 * 4);
    #pragma unroll
    for (int c = 1; c < 16; ++c)
        m = f4mul(m, LD4(P2 + c * 131072 + idx4 * 4));
    const float4 r = make_float4(1.f - m.x, 1.f - m.y, 1.f - m.z, 1.f - m.w);
    *(float4*)(out + idx4 * 4) = r;
}

extern "C" void kernel_launch(void* const* d_in, const int* in_sizes, int n_in,
                              void* d_out, int out_size, void* d_ws, size_t ws_size,
                              hipStream_t stream)
{
    const float* in = (const float*)d_in[0];   // [128][256][8]
    const float* cw = (const float*)d_in[1];   // [256][512][8]
    const float* cs = (const float*)d_in[2];   // [256][512][8]
    const float* dw = (const float*)d_in[3];   // [512][128][8]
    float* outp = (float*)d_out;               // [128][128][8]
    float* P1   = (float*)d_ws;                // 16 MB
    float* P2   = (float*)d_ws + 4194304;      // 8 MB

    k_stage1<<<2048, 256, 0, stream>>>(in, cw, cs, P1);
    k_stage2<<<1024, 256, 0, stream>>>(dw, P1, P2);
    k_comb2<<<128, 256, 0, stream>>>(P2, outp);
}